// Round 13
// baseline (523.954 us; speedup 1.0000x reference)
//
#include <hip/hip_runtime.h>
#include <hip/hip_bf16.h>
#include <stdint.h>

#define B_ 8192
#define D_ 1024
#define H_ 4096
#define O_ 1024
#define E_ 8

typedef __attribute__((ext_vector_type(8))) short bf16x8;
typedef __attribute__((ext_vector_type(4))) float f32x4;

__device__ __forceinline__ ushort f2bf(float f) {
  uint32_t u = __builtin_bit_cast(uint32_t, f);
  uint32_t r = (u + 0x7FFFu + ((u >> 16) & 1u)) >> 16;
  return (ushort)r;
}

__device__ __forceinline__ void gload_lds16(const ushort* g, ushort* l) {
  __builtin_amdgcn_global_load_lds(
      (__attribute__((address_space(1))) void*)g,
      (__attribute__((address_space(3))) void*)l, 16, 0, 0);
}

// ------------- per-expert transpose + cvt: in [E][R][C] f32 -> out [E][C][R] bf16 -------------
__global__ void transpose_cvt(const float* __restrict__ in, ushort* __restrict__ out,
                              int R, int C) {
  __shared__ ushort t2[64][72];
  int c0 = blockIdx.x * 64, r0 = blockIdx.y * 64;
  size_t eoff = (size_t)blockIdx.z * R * C;
  int tid = threadIdx.x;
#pragma unroll
  for (int i = 0; i < 4; ++i) {
    int idx = i * 256 + tid;
    int r = idx >> 4, c4 = (idx & 15) * 4;
    float4 v = *(const float4*)(in + eoff + (size_t)(r0 + r) * C + c0 + c4);
    t2[c4 + 0][r] = f2bf(v.x); t2[c4 + 1][r] = f2bf(v.y);
    t2[c4 + 2][r] = f2bf(v.z); t2[c4 + 3][r] = f2bf(v.w);
  }
  __syncthreads();
#pragma unroll
  for (int i = 0; i < 4; ++i) {
    int idx = i * 256 + tid;
    int cc = idx >> 4, r4 = (idx & 15) * 4;
    *(ushort4*)&out[eoff + (size_t)(c0 + cc) * R + r0 + r4] = *(const ushort4*)&t2[cc][r4];
  }
}

// ---------------- gating: logits, top-2, softmax; fused x->bf16; NO atomics ----------------
__global__ void gating_k(const float* __restrict__ x, const float* __restrict__ Wg,
                         const float* __restrict__ bg, float* __restrict__ gates,
                         float* __restrict__ topi, int* __restrict__ exp_a,
                         float* __restrict__ gate_a, ushort* __restrict__ xb) {
  int row = blockIdx.x * 4 + (threadIdx.x >> 6);
  int lane = threadIdx.x & 63;
  const float* xr = x + (size_t)row * D_;
  ushort* xbr = xb + (size_t)row * D_;
  float acc[8];
#pragma unroll
  for (int e = 0; e < 8; ++e) acc[e] = 0.f;
  for (int j = 0; j < 16; ++j) {
    int d = j * 64 + lane;
    float xv = xr[d];
    xbr[d] = f2bf(xv);
    const float4* wp = (const float4*)(Wg + d * 8);
    float4 w0 = wp[0], w1 = wp[1];
    acc[0] = fmaf(xv, w0.x, acc[0]); acc[1] = fmaf(xv, w0.y, acc[1]);
    acc[2] = fmaf(xv, w0.z, acc[2]); acc[3] = fmaf(xv, w0.w, acc[3]);
    acc[4] = fmaf(xv, w1.x, acc[4]); acc[5] = fmaf(xv, w1.y, acc[5]);
    acc[6] = fmaf(xv, w1.z, acc[6]); acc[7] = fmaf(xv, w1.w, acc[7]);
  }
#pragma unroll
  for (int e = 0; e < 8; ++e) {
#pragma unroll
    for (int off = 32; off; off >>= 1) acc[e] += __shfl_xor(acc[e], off);
  }
  if (lane == 0) {
    float v0 = -1e30f, v1 = -1e30f; int i0 = 0, i1 = 0;
#pragma unroll
    for (int e = 0; e < 8; ++e) {
      float ve = acc[e] + bg[e];
      if (ve > v0)      { v1 = v0; i1 = i0; v0 = ve; i0 = e; }
      else if (ve > v1) { v1 = ve; i1 = e; }
    }
    float t = expf(v1 - v0);
    float g0 = 1.f / (1.f + t), g1 = t / (1.f + t);
#pragma unroll
    for (int e = 0; e < 8; ++e)
      gates[row * 8 + e] = (e == i0) ? g0 : ((e == i1) ? g1 : 0.f);
    topi[row * 2 + 0] = (float)i0;
    topi[row * 2 + 1] = (float)i1;
    exp_a[row * 2 + 0] = i0;
    exp_a[row * 2 + 1] = i1;
    gate_a[row * 2 + 0] = g0;
    gate_a[row * 2 + 1] = g1;
  }
}

// ---------------- histogram + prefix: one block, ballot-based, no global atomics ----------------
__global__ void count_prefix_k(const int* __restrict__ exp_a, int* __restrict__ counts,
                               int* __restrict__ offs, int* __restrict__ cursors) {
  __shared__ int hist[8];
  int tid = threadIdx.x, lane = tid & 63;
  if (tid < 8) hist[tid] = 0;
  __syncthreads();
  int c[8];
#pragma unroll
  for (int k = 0; k < 8; ++k) c[k] = 0;
  for (int i = tid; i < 2 * B_; i += 256) {
    int e = exp_a[i];
#pragma unroll
    for (int k = 0; k < 8; ++k) {
      unsigned long long m = __ballot(e == k);
      c[k] += (lane == 0) ? __popcll(m) : 0;
    }
  }
  if (lane == 0) {
#pragma unroll
    for (int k = 0; k < 8; ++k) atomicAdd(&hist[k], c[k]);
  }
  __syncthreads();
  if (tid == 0) {
    int s = 0;
#pragma unroll
    for (int e = 0; e < 8; ++e) {
      int ce = hist[e];
      counts[e] = ce; offs[e] = s; cursors[e] = s; s += ce;
    }
  }
}

// ---------------- scatter: wave-aggregated atomics (<=8 per wave) ----------------
__global__ void scatter_k(const int* __restrict__ exp_a, int* __restrict__ cursors,
                          int* __restrict__ rows, int* __restrict__ slot_of) {
  int a = blockIdx.x * 256 + threadIdx.x;            // 0..16383
  int lane = threadIdx.x & 63;
  int e = exp_a[a];
  unsigned long long lt = (lane == 63) ? ~0ull >> 1 : ((1ull << (lane & 63)) - 1);
  int slot = 0;
#pragma unroll
  for (int k = 0; k < 8; ++k) {
    unsigned long long m = __ballot(e == k);
    if (m) {
      int leader = __ffsll((unsigned long long)m) - 1;
      int base = 0;
      if (lane == leader) base = atomicAdd(&cursors[k], __popcll(m));
      base = __shfl(base, leader);
      if (e == k) slot = base + __popcll(m & lt);
    }
  }
  rows[slot] = a >> 1;
  slot_of[a] = slot;
}

// ============ grouped expert GEMM: 128x128x64, dbuf + counted vmcnt, 2 blocks/CU, 8 waves ============
// R12's verified schedule, but 512 threads (8 waves, 2M x 4N, per-wave 64x32): 16 waves/CU
// (4/SIMD) for deeper SIMD-level MFMA/ds_read/vmem co-issue at the same 64 KiB LDS and
// 2-block residency. Per tile: {vmcnt(4); barrier; read 16 frags; MFMA m0..2; lgkmcnt(0);
// barrier; stage t+2 (4 gload_lds); MFMA m3}.
template <int LAYER>
__global__ __launch_bounds__(512, 2)
void moe_gemm(const ushort* __restrict__ Abase, const ushort* __restrict__ Bbase,
              const float* __restrict__ bias, ushort* __restrict__ hout,
              float* __restrict__ part, const int* __restrict__ rows,
              const int* __restrict__ counts, const int* __restrict__ offs) {
  constexpr int KD = (LAYER == 1) ? D_ : H_;   // K dim
  constexpr int ND = (LAYER == 1) ? H_ : O_;   // N dim (rows of Bt)
  constexpr int NT = KD / 64;
  constexpr int NTILE = ND / 128;              // tiles in N
  constexpr int MTILE = 24;                    // padded tiles in M (3072 rows = mean+24sigma)
  constexpr int SNB = NTILE / 4;               // supertile columns

  int nwg = NTILE * MTILE * E_;
  int gid = blockIdx.x + NTILE * (blockIdx.y + MTILE * blockIdx.z);
  int sid = (gid & 7) * (nwg >> 3) + (gid >> 3);
  int e = sid / (NTILE * MTILE);
  int r = sid % (NTILE * MTILE);
  int st = r >> 4, u = r & 15;
  int mb = (st / SNB) * 4 + (u >> 2);
  int nb = (st % SNB) * 4 + (u & 3);

  int cnt = counts[e];
  int m0 = mb * 128;
  if (m0 >= cnt) return;
  int n0 = nb * 128;
  int off = offs[e];

  __shared__ __align__(16) ushort lds[32768];   // 64 KiB: buf bb at bb*16384 (ushorts)

  int tid = threadIdx.x;
  int wid = tid >> 6, lane = tid & 63;
  int wr = wid >> 2, wc = wid & 3;              // 2M x 4N, per-wave 64x32

  int xorc = ((lane & 7) ^ (lane >> 3)) << 3;   // inverse-swizzled k-seg (elements)
  const ushort* pA[2];
  const ushort* pB[2];
#pragma unroll
  for (int c = 0; c < 2; ++c) {
    int trow = c * 64 + (tid >> 3);             // row in 128-tile (tid>>3: 0..63)
    int slot = m0 + trow; slot = (slot < cnt) ? slot : (cnt - 1);
    size_t arow;
    if (LAYER == 1) arow = (size_t)rows[off + slot];
    else            arow = (size_t)(off + slot);
    pA[c] = Abase + arow * KD + xorc;
    pB[c] = Bbase + ((size_t)e * ND + n0 + trow) * KD + xorc;
  }

  f32x4 acc[4][2];
  f32x4 z = {0.f, 0.f, 0.f, 0.f};
#pragma unroll
  for (int m = 0; m < 4; ++m)
#pragma unroll
    for (int n = 0; n < 2; ++n) acc[m][n] = z;

  int lrow = lane & 15;
  int lkb = (lane >> 4) << 4;
  int swz = (lane & 7) << 4;

  // prologue: stage tiles 0 and 1 (4 loads/thread per tile)
#pragma unroll
  for (int tt = 0; tt < 2; ++tt)
#pragma unroll
    for (int c = 0; c < 2; ++c) {
      ushort* base = lds + tt * 16384 + c * 4096 + wid * 512;
      gload_lds16(pA[c], base);
      gload_lds16(pB[c], base + 8192);
      pA[c] += 64; pB[c] += 64;
    }

#pragma unroll 1
  for (int t = 0; t < NT; ++t) {
    if (t < NT - 1) asm volatile("s_waitcnt vmcnt(4)" ::: "memory");
    else            asm volatile("s_waitcnt vmcnt(0)" ::: "memory");
    __builtin_amdgcn_s_barrier();
    const char* bufA = (const char*)lds + (t & 1) * 32768;
    const char* bufB = bufA + 16384;

    bf16x8 bfr[2][2], af[4][2];
#pragma unroll
    for (int n = 0; n < 2; ++n)
#pragma unroll
      for (int ks = 0; ks < 2; ++ks) {
        int rr = wc * 32 + n * 16 + lrow;
        bfr[n][ks] = *(const bf16x8*)(bufB + rr * 128 + ((ks * 64 + lkb) ^ swz));
      }
#pragma unroll
    for (int m = 0; m < 4; ++m)
#pragma unroll
      for (int ks = 0; ks < 2; ++ks) {
        int rr = wr * 64 + m * 16 + lrow;
        af[m][ks] = *(const bf16x8*)(bufA + rr * 128 + ((ks * 64 + lkb) ^ swz));
      }

    __builtin_amdgcn_s_setprio(1);
#pragma unroll
    for (int m = 0; m < 3; ++m)
#pragma unroll
      for (int n = 0; n < 2; ++n)
#pragma unroll
        for (int ks = 0; ks < 2; ++ks)
          acc[m][n] = __builtin_amdgcn_mfma_f32_16x16x32_bf16(
              bfr[n][ks], af[m][ks], acc[m][n], 0, 0, 0);

    asm volatile("s_waitcnt lgkmcnt(0)" ::: "memory");
    __builtin_amdgcn_s_barrier();
    if (t + 2 < NT) {
#pragma unroll
      for (int c = 0; c < 2; ++c) {
        ushort* base = lds + (t & 1) * 16384 + c * 4096 + wid * 512;
        gload_lds16(pA[c], base);
        gload_lds16(pB[c], base + 8192);
        pA[c] += 64; pB[c] += 64;
      }
    }
#pragma unroll
    for (int n = 0; n < 2; ++n)
#pragma unroll
      for (int ks = 0; ks < 2; ++ks)
        acc[3][n] = __builtin_amdgcn_mfma_f32_16x16x32_bf16(
            bfr[n][ks], af[3][ks], acc[3][n], 0, 0, 0);
    __builtin_amdgcn_s_setprio(0);
  }

  // --- epilogue (swapped C/D): M-row = ... + (lane&15); N-col = ... + (lane>>4)*4 + j ---
  const float* bias_e = bias + (size_t)e * ND;
  int colb = n0 + wc * 32 + ((lane >> 4) << 2);
  int rowb = m0 + wr * 64 + (lane & 15);
#pragma unroll
  for (int m = 0; m < 4; ++m) {
    int rr = rowb + m * 16;
    if (rr < cnt) {
      size_t gro = (size_t)(off + rr) * ND;
#pragma unroll
      for (int n = 0; n < 2; ++n) {
        int cg = colb + n * 16;
        float4 bv = *(const float4*)(bias_e + cg);
        f32x4 a = acc[m][n];
        if (LAYER == 1) {
          ushort4 o;
          o.x = f2bf(fmaxf(a[0] + bv.x, 0.f));
          o.y = f2bf(fmaxf(a[1] + bv.y, 0.f));
          o.z = f2bf(fmaxf(a[2] + bv.z, 0.f));
          o.w = f2bf(fmaxf(a[3] + bv.w, 0.f));
          *(ushort4*)&hout[gro + cg] = o;
        } else {
          float4 o;
          o.x = a[0] + bv.x; o.y = a[1] + bv.y;
          o.z = a[2] + bv.z; o.w = a[3] + bv.w;
          *(float4*)&part[gro + cg] = o;
        }
      }
    }
  }
}

// ---------------- combine: out[b] = g0*part[s0] + g1*part[s1] ----------------
__global__ void combine_k(const float* __restrict__ part, const int* __restrict__ slot_of,
                          const float* __restrict__ gate_a, float* __restrict__ out) {
  int i = blockIdx.x * 256 + threadIdx.x;  // over B*O/4
  int b = i >> 8;
  int c4 = i & 255;
  int s0 = slot_of[b * 2], s1 = slot_of[b * 2 + 1];
  float g0 = gate_a[b * 2], g1 = gate_a[b * 2 + 1];
  float4 p0 = ((const float4*)(part + (size_t)s0 * O_))[c4];
  float4 p1 = ((const float4*)(part + (size_t)s1 * O_))[c4];
  float4 r;
  r.x = g0 * p0.x + g1 * p1.x;
  r.y = g0 * p0.y + g1 * p1.y;
  r.z = g0 * p0.z + g1 * p1.z;
  r.w = g0 * p0.w + g1 * p1.w;
  ((float4*)(out + (size_t)b * O_))[c4] = r;
}

// ---------------- importance / load (deterministic fixed-tree reduce) ----------------
__global__ void importance_k(const float* __restrict__ gates, float* __restrict__ load,
                             float* __restrict__ imp) {
  int e = blockIdx.x;
  float s = 0.f;
  for (int b = threadIdx.x; b < B_; b += 256) s += gates[b * 8 + e];
  __shared__ float red[4];
#pragma unroll
  for (int off = 32; off; off >>= 1) s += __shfl_xor(s, off);
  if ((threadIdx.x & 63) == 0) red[threadIdx.x >> 6] = s;
  __syncthreads();
  if (threadIdx.x == 0) {
    float t = (red[0] + red[1]) + (red[2] + red[3]);
    imp[e] = t;
    load[e] = t * (1.f / (float)B_);
  }
}

extern "C" void kernel_launch(void* const* d_in, const int* in_sizes, int n_in,
                              void* d_out, int out_size, void* d_ws, size_t ws_size,
                              hipStream_t stream) {
  const float* x  = (const float*)d_in[0];
  const float* Wg = (const float*)d_in[1];
  const float* bg = (const float*)d_in[2];
  const float* W1 = (const float*)d_in[3];
  const float* b1 = (const float*)d_in[4];
  const float* W2 = (const float*)d_in[5];
  const float* b2 = (const float*)d_in[6];

  float* out = (float*)d_out;
  float* out_y     = out;                 // [B,O]  8388608
  float* out_gates = out + 8388608;       // [B,E]  65536
  float* out_load  = out + 8454144;       // [E]    8
  float* out_imp   = out + 8454152;       // [E]    8
  float* out_topi  = out + 8454160;       // [B,K]  16384 (as float)

  char* w = (char*)d_ws;
  ushort* x_bf    = (ushort*)(w);                      // 16,777,216 B
  ushort* w1t     = (ushort*)(w + 16777216);           // 67,108,864 B  [E][H][D]
  ushort* w2t     = (ushort*)(w + 83886080);           // 67,108,864 B  [E][O][H]
  ushort* h_buf   = (ushort*)(w + 150994944);          // 134,217,728 B [16384][H]
  float*  part    = (float*)(w + 285212672);           // 67,108,864 B  [16384][O]
  int*    rows    = (int*)(w + 352321536);             // 65536 B
  int*    slot_of = (int*)(w + 352387072);             // 65536 B
  int*    exp_a   = (int*)(w + 352452608);             // 65536 B
  float*  gate_a  = (float*)(w + 352518144);           // 65536 B
  int*    counts  = (int*)(w + 352583680);             // 32 B
  int*    offs    = (int*)(w + 352583712);             // 32 B
  int*    cursors = (int*)(w + 352583744);             // 32 B

  (void)in_sizes; (void)n_in; (void)out_size; (void)ws_size;

  transpose_cvt<<<dim3(H_ / 64, D_ / 64, E_), 256, 0, stream>>>(W1, w1t, D_, H_);
  transpose_cvt<<<dim3(O_ / 64, H_ / 64, E_), 256, 0, stream>>>(W2, w2t, H_, O_);

  gating_k<<<B_ / 4, 256, 0, stream>>>(x, Wg, bg, out_gates, out_topi, exp_a, gate_a, x_bf);
  count_prefix_k<<<1, 256, 0, stream>>>(exp_a, counts, offs, cursors);
  scatter_k<<<64, 256, 0, stream>>>(exp_a, cursors, rows, slot_of);

  moe_gemm<1><<<dim3(H_ / 128, 24, E_), 512, 0, stream>>>(x_bf, w1t, b1, h_buf, part,
                                                          rows, counts, offs);
  moe_gemm<2><<<dim3(O_ / 128, 24, E_), 512, 0, stream>>>(h_buf, w2t, b2, h_buf, part,
                                                          rows, counts, offs);

  combine_k<<<B_ * O_ / 4 / 256, 256, 0, stream>>>(part, slot_of, gate_a, out_y);
  importance_k<<<E_, 256, 0, stream>>>(out_gates, out_load, out_imp);
}

// Round 14
// 511.719 us; speedup vs baseline: 1.0239x; 1.0239x over previous
//
#include <hip/hip_runtime.h>
#include <hip/hip_bf16.h>
#include <stdint.h>

#define B_ 8192
#define D_ 1024
#define H_ 4096
#define O_ 1024
#define E_ 8

typedef __attribute__((ext_vector_type(8))) short bf16x8;
typedef __attribute__((ext_vector_type(4))) float f32x4;

__device__ __forceinline__ ushort f2bf(float f) {
  uint32_t u = __builtin_bit_cast(uint32_t, f);
  uint32_t r = (u + 0x7FFFu + ((u >> 16) & 1u)) >> 16;
  return (ushort)r;
}

__device__ __forceinline__ void gload_lds16(const ushort* g, ushort* l) {
  __builtin_amdgcn_global_load_lds(
      (__attribute__((address_space(1))) void*)g,
      (__attribute__((address_space(3))) void*)l, 16, 0, 0);
}

// ------------- per-expert transpose + cvt: in [E][R][C] f32 -> out [E][C][R] bf16 -------------
__global__ void transpose_cvt(const float* __restrict__ in, ushort* __restrict__ out,
                              int R, int C) {
  __shared__ ushort t2[64][72];
  int c0 = blockIdx.x * 64, r0 = blockIdx.y * 64;
  size_t eoff = (size_t)blockIdx.z * R * C;
  int tid = threadIdx.x;
#pragma unroll
  for (int i = 0; i < 4; ++i) {
    int idx = i * 256 + tid;
    int r = idx >> 4, c4 = (idx & 15) * 4;
    float4 v = *(const float4*)(in + eoff + (size_t)(r0 + r) * C + c0 + c4);
    t2[c4 + 0][r] = f2bf(v.x); t2[c4 + 1][r] = f2bf(v.y);
    t2[c4 + 2][r] = f2bf(v.z); t2[c4 + 3][r] = f2bf(v.w);
  }
  __syncthreads();
#pragma unroll
  for (int i = 0; i < 4; ++i) {
    int idx = i * 256 + tid;
    int cc = idx >> 4, r4 = (idx & 15) * 4;
    *(ushort4*)&out[eoff + (size_t)(c0 + cc) * R + r0 + r4] = *(const ushort4*)&t2[cc][r4];
  }
}

// ---------------- gating: logits, top-2, softmax; fused x->bf16; NO atomics ----------------
__global__ void gating_k(const float* __restrict__ x, const float* __restrict__ Wg,
                         const float* __restrict__ bg, float* __restrict__ gates,
                         float* __restrict__ topi, int* __restrict__ exp_a,
                         float* __restrict__ gate_a, ushort* __restrict__ xb) {
  int row = blockIdx.x * 4 + (threadIdx.x >> 6);
  int lane = threadIdx.x & 63;
  const float* xr = x + (size_t)row * D_;
  ushort* xbr = xb + (size_t)row * D_;
  float acc[8];
#pragma unroll
  for (int e = 0; e < 8; ++e) acc[e] = 0.f;
  for (int j = 0; j < 16; ++j) {
    int d = j * 64 + lane;
    float xv = xr[d];
    xbr[d] = f2bf(xv);
    const float4* wp = (const float4*)(Wg + d * 8);
    float4 w0 = wp[0], w1 = wp[1];
    acc[0] = fmaf(xv, w0.x, acc[0]); acc[1] = fmaf(xv, w0.y, acc[1]);
    acc[2] = fmaf(xv, w0.z, acc[2]); acc[3] = fmaf(xv, w0.w, acc[3]);
    acc[4] = fmaf(xv, w1.x, acc[4]); acc[5] = fmaf(xv, w1.y, acc[5]);
    acc[6] = fmaf(xv, w1.z, acc[6]); acc[7] = fmaf(xv, w1.w, acc[7]);
  }
#pragma unroll
  for (int e = 0; e < 8; ++e) {
#pragma unroll
    for (int off = 32; off; off >>= 1) acc[e] += __shfl_xor(acc[e], off);
  }
  if (lane == 0) {
    float v0 = -1e30f, v1 = -1e30f; int i0 = 0, i1 = 0;
#pragma unroll
    for (int e = 0; e < 8; ++e) {
      float ve = acc[e] + bg[e];
      if (ve > v0)      { v1 = v0; i1 = i0; v0 = ve; i0 = e; }
      else if (ve > v1) { v1 = ve; i1 = e; }
    }
    float t = expf(v1 - v0);
    float g0 = 1.f / (1.f + t), g1 = t / (1.f + t);
#pragma unroll
    for (int e = 0; e < 8; ++e)
      gates[row * 8 + e] = (e == i0) ? g0 : ((e == i1) ? g1 : 0.f);
    topi[row * 2 + 0] = (float)i0;
    topi[row * 2 + 1] = (float)i1;
    exp_a[row * 2 + 0] = i0;
    exp_a[row * 2 + 1] = i1;
    gate_a[row * 2 + 0] = g0;
    gate_a[row * 2 + 1] = g1;
  }
}

// ---------------- histogram + prefix: one block, ballot-based, no global atomics ----------------
__global__ void count_prefix_k(const int* __restrict__ exp_a, int* __restrict__ counts,
                               int* __restrict__ offs, int* __restrict__ cursors) {
  __shared__ int hist[8];
  int tid = threadIdx.x, lane = tid & 63;
  if (tid < 8) hist[tid] = 0;
  __syncthreads();
  int c[8];
#pragma unroll
  for (int k = 0; k < 8; ++k) c[k] = 0;
  for (int i = tid; i < 2 * B_; i += 256) {
    int e = exp_a[i];
#pragma unroll
    for (int k = 0; k < 8; ++k) {
      unsigned long long m = __ballot(e == k);
      c[k] += (lane == 0) ? __popcll(m) : 0;
    }
  }
  if (lane == 0) {
#pragma unroll
    for (int k = 0; k < 8; ++k) atomicAdd(&hist[k], c[k]);
  }
  __syncthreads();
  if (tid == 0) {
    int s = 0;
#pragma unroll
    for (int e = 0; e < 8; ++e) {
      int ce = hist[e];
      counts[e] = ce; offs[e] = s; cursors[e] = s; s += ce;
    }
  }
}

// ---------------- scatter: wave-aggregated atomics (<=8 per wave) ----------------
__global__ void scatter_k(const int* __restrict__ exp_a, int* __restrict__ cursors,
                          int* __restrict__ rows, int* __restrict__ slot_of) {
  int a = blockIdx.x * 256 + threadIdx.x;            // 0..16383
  int lane = threadIdx.x & 63;
  int e = exp_a[a];
  unsigned long long lt = (lane == 63) ? ~0ull >> 1 : ((1ull << (lane & 63)) - 1);
  int slot = 0;
#pragma unroll
  for (int k = 0; k < 8; ++k) {
    unsigned long long m = __ballot(e == k);
    if (m) {
      int leader = __ffsll((unsigned long long)m) - 1;
      int base = 0;
      if (lane == leader) base = atomicAdd(&cursors[k], __popcll(m));
      base = __shfl(base, leader);
      if (e == k) slot = base + __popcll(m & lt);
    }
  }
  rows[slot] = a >> 1;
  slot_of[a] = slot;
}

// ============ grouped expert GEMM: 128x128x64, dbuf + counted vmcnt, 2 blocks/CU, 8 waves ============
// R13 core (frozen). LAYER 2 now writes bf16 partials (ushort4) — halves part traffic.
template <int LAYER>
__global__ __launch_bounds__(512, 2)
void moe_gemm(const ushort* __restrict__ Abase, const ushort* __restrict__ Bbase,
              const float* __restrict__ bias, ushort* __restrict__ hout,
              ushort* __restrict__ part, const int* __restrict__ rows,
              const int* __restrict__ counts, const int* __restrict__ offs) {
  constexpr int KD = (LAYER == 1) ? D_ : H_;   // K dim
  constexpr int ND = (LAYER == 1) ? H_ : O_;   // N dim (rows of Bt)
  constexpr int NT = KD / 64;
  constexpr int NTILE = ND / 128;              // tiles in N
  constexpr int MTILE = 20;                    // padded tiles in M (2560 rows = mean+12sigma)
  constexpr int SNB = NTILE / 4;               // supertile columns

  int nwg = NTILE * MTILE * E_;
  int gid = blockIdx.x + NTILE * (blockIdx.y + MTILE * blockIdx.z);
  int sid = (gid & 7) * (nwg >> 3) + (gid >> 3);
  int e = sid / (NTILE * MTILE);
  int r = sid % (NTILE * MTILE);
  int st = r >> 4, u = r & 15;
  int mb = (st / SNB) * 4 + (u >> 2);
  int nb = (st % SNB) * 4 + (u & 3);

  int cnt = counts[e];
  int m0 = mb * 128;
  if (m0 >= cnt) return;
  int n0 = nb * 128;
  int off = offs[e];

  __shared__ __align__(16) ushort lds[32768];   // 64 KiB: buf bb at bb*16384 (ushorts)

  int tid = threadIdx.x;
  int wid = tid >> 6, lane = tid & 63;
  int wr = wid >> 2, wc = wid & 3;              // 2M x 4N, per-wave 64x32

  int xorc = ((lane & 7) ^ (lane >> 3)) << 3;   // inverse-swizzled k-seg (elements)
  const ushort* pA[2];
  const ushort* pB[2];
#pragma unroll
  for (int c = 0; c < 2; ++c) {
    int trow = c * 64 + (tid >> 3);             // row in 128-tile (tid>>3: 0..63)
    int slot = m0 + trow; slot = (slot < cnt) ? slot : (cnt - 1);
    size_t arow;
    if (LAYER == 1) arow = (size_t)rows[off + slot];
    else            arow = (size_t)(off + slot);
    pA[c] = Abase + arow * KD + xorc;
    pB[c] = Bbase + ((size_t)e * ND + n0 + trow) * KD + xorc;
  }

  f32x4 acc[4][2];
  f32x4 z = {0.f, 0.f, 0.f, 0.f};
#pragma unroll
  for (int m = 0; m < 4; ++m)
#pragma unroll
    for (int n = 0; n < 2; ++n) acc[m][n] = z;

  int lrow = lane & 15;
  int lkb = (lane >> 4) << 4;
  int swz = (lane & 7) << 4;

  // prologue: stage tiles 0 and 1 (4 loads/thread per tile)
#pragma unroll
  for (int tt = 0; tt < 2; ++tt)
#pragma unroll
    for (int c = 0; c < 2; ++c) {
      ushort* base = lds + tt * 16384 + c * 4096 + wid * 512;
      gload_lds16(pA[c], base);
      gload_lds16(pB[c], base + 8192);
      pA[c] += 64; pB[c] += 64;
    }

#pragma unroll 1
  for (int t = 0; t < NT; ++t) {
    if (t < NT - 1) asm volatile("s_waitcnt vmcnt(4)" ::: "memory");
    else            asm volatile("s_waitcnt vmcnt(0)" ::: "memory");
    __builtin_amdgcn_s_barrier();
    const char* bufA = (const char*)lds + (t & 1) * 32768;
    const char* bufB = bufA + 16384;

    bf16x8 bfr[2][2], af[4][2];
#pragma unroll
    for (int n = 0; n < 2; ++n)
#pragma unroll
      for (int ks = 0; ks < 2; ++ks) {
        int rr = wc * 32 + n * 16 + lrow;
        bfr[n][ks] = *(const bf16x8*)(bufB + rr * 128 + ((ks * 64 + lkb) ^ swz));
      }
#pragma unroll
    for (int m = 0; m < 4; ++m)
#pragma unroll
      for (int ks = 0; ks < 2; ++ks) {
        int rr = wr * 64 + m * 16 + lrow;
        af[m][ks] = *(const bf16x8*)(bufA + rr * 128 + ((ks * 64 + lkb) ^ swz));
      }

    __builtin_amdgcn_s_setprio(1);
#pragma unroll
    for (int m = 0; m < 3; ++m)
#pragma unroll
      for (int n = 0; n < 2; ++n)
#pragma unroll
        for (int ks = 0; ks < 2; ++ks)
          acc[m][n] = __builtin_amdgcn_mfma_f32_16x16x32_bf16(
              bfr[n][ks], af[m][ks], acc[m][n], 0, 0, 0);

    asm volatile("s_waitcnt lgkmcnt(0)" ::: "memory");
    __builtin_amdgcn_s_barrier();
    if (t + 2 < NT) {
#pragma unroll
      for (int c = 0; c < 2; ++c) {
        ushort* base = lds + (t & 1) * 16384 + c * 4096 + wid * 512;
        gload_lds16(pA[c], base);
        gload_lds16(pB[c], base + 8192);
        pA[c] += 64; pB[c] += 64;
      }
    }
#pragma unroll
    for (int n = 0; n < 2; ++n)
#pragma unroll
      for (int ks = 0; ks < 2; ++ks)
        acc[3][n] = __builtin_amdgcn_mfma_f32_16x16x32_bf16(
            bfr[n][ks], af[3][ks], acc[3][n], 0, 0, 0);
    __builtin_amdgcn_s_setprio(0);
  }

  // --- epilogue (swapped C/D): M-row = ... + (lane&15); N-col = ... + (lane>>4)*4 + j ---
  const float* bias_e = bias + (size_t)e * ND;
  int colb = n0 + wc * 32 + ((lane >> 4) << 2);
  int rowb = m0 + wr * 64 + (lane & 15);
#pragma unroll
  for (int m = 0; m < 4; ++m) {
    int rr = rowb + m * 16;
    if (rr < cnt) {
      size_t gro = (size_t)(off + rr) * ND;
#pragma unroll
      for (int n = 0; n < 2; ++n) {
        int cg = colb + n * 16;
        float4 bv = *(const float4*)(bias_e + cg);
        f32x4 a = acc[m][n];
        ushort4 o;
        if (LAYER == 1) {
          o.x = f2bf(fmaxf(a[0] + bv.x, 0.f));
          o.y = f2bf(fmaxf(a[1] + bv.y, 0.f));
          o.z = f2bf(fmaxf(a[2] + bv.z, 0.f));
          o.w = f2bf(fmaxf(a[3] + bv.w, 0.f));
          *(ushort4*)&hout[gro + cg] = o;
        } else {
          o.x = f2bf(a[0] + bv.x); o.y = f2bf(a[1] + bv.y);
          o.z = f2bf(a[2] + bv.z); o.w = f2bf(a[3] + bv.w);
          *(ushort4*)&part[gro + cg] = o;
        }
      }
    }
  }
}

// ---------------- combine: out[b] = g0*part[s0] + g1*part[s1]  (bf16 partials) ----------------
__global__ void combine_k(const ushort* __restrict__ part, const int* __restrict__ slot_of,
                          const float* __restrict__ gate_a, float* __restrict__ out) {
  int i = blockIdx.x * 256 + threadIdx.x;  // over B*O/8
  int b = i >> 7;
  int c8 = (i & 127) * 8;
  int s0 = slot_of[b * 2], s1 = slot_of[b * 2 + 1];
  float g0 = gate_a[b * 2], g1 = gate_a[b * 2 + 1];
  uint4 p0 = *(const uint4*)&part[(size_t)s0 * O_ + c8];
  uint4 p1 = *(const uint4*)&part[(size_t)s1 * O_ + c8];
  float4 r0, r1;
#define BLEND(uu0, uu1, dst_lo, dst_hi)                                              \
  {                                                                                  \
    float a0 = __builtin_bit_cast(float, (uint32_t)((uu0) << 16));                   \
    float a1 = __builtin_bit_cast(float, (uint32_t)((uu0) & 0xFFFF0000u));           \
    float b0 = __builtin_bit_cast(float, (uint32_t)((uu1) << 16));                   \
    float b1 = __builtin_bit_cast(float, (uint32_t)((uu1) & 0xFFFF0000u));           \
    dst_lo = g0 * a0 + g1 * b0;                                                      \
    dst_hi = g0 * a1 + g1 * b1;                                                      \
  }
  BLEND(p0.x, p1.x, r0.x, r0.y);
  BLEND(p0.y, p1.y, r0.z, r0.w);
  BLEND(p0.z, p1.z, r1.x, r1.y);
  BLEND(p0.w, p1.w, r1.z, r1.w);
#undef BLEND
  float* ob = out + (size_t)b * O_ + c8;
  *(float4*)ob = r0;
  *(float4*)(ob + 4) = r1;
}

// ---------------- importance / load (deterministic fixed-tree reduce) ----------------
__global__ void importance_k(const float* __restrict__ gates, float* __restrict__ load,
                             float* __restrict__ imp) {
  int e = blockIdx.x;
  float s = 0.f;
  for (int b = threadIdx.x; b < B_; b += 256) s += gates[b * 8 + e];
  __shared__ float red[4];
#pragma unroll
  for (int off = 32; off; off >>= 1) s += __shfl_xor(s, off);
  if ((threadIdx.x & 63) == 0) red[threadIdx.x >> 6] = s;
  __syncthreads();
  if (threadIdx.x == 0) {
    float t = (red[0] + red[1]) + (red[2] + red[3]);
    imp[e] = t;
    load[e] = t * (1.f / (float)B_);
  }
}

extern "C" void kernel_launch(void* const* d_in, const int* in_sizes, int n_in,
                              void* d_out, int out_size, void* d_ws, size_t ws_size,
                              hipStream_t stream) {
  const float* x  = (const float*)d_in[0];
  const float* Wg = (const float*)d_in[1];
  const float* bg = (const float*)d_in[2];
  const float* W1 = (const float*)d_in[3];
  const float* b1 = (const float*)d_in[4];
  const float* W2 = (const float*)d_in[5];
  const float* b2 = (const float*)d_in[6];

  float* out = (float*)d_out;
  float* out_y     = out;                 // [B,O]  8388608
  float* out_gates = out + 8388608;       // [B,E]  65536
  float* out_load  = out + 8454144;       // [E]    8
  float* out_imp   = out + 8454152;       // [E]    8
  float* out_topi  = out + 8454160;       // [B,K]  16384 (as float)

  char* w = (char*)d_ws;
  ushort* x_bf    = (ushort*)(w);                      // 16,777,216 B
  ushort* w1t     = (ushort*)(w + 16777216);           // 67,108,864 B  [E][H][D]
  ushort* w2t     = (ushort*)(w + 83886080);           // 67,108,864 B  [E][O][H]
  ushort* h_buf   = (ushort*)(w + 150994944);          // 134,217,728 B [16384][H]
  ushort* part    = (ushort*)(w + 285212672);          // 33,554,432 B  [16384][O] bf16
  int*    rows    = (int*)(w + 352321536);             // 65536 B
  int*    slot_of = (int*)(w + 352387072);             // 65536 B
  int*    exp_a   = (int*)(w + 352452608);             // 65536 B
  float*  gate_a  = (float*)(w + 352518144);           // 65536 B
  int*    counts  = (int*)(w + 352583680);             // 32 B
  int*    offs    = (int*)(w + 352583712);             // 32 B
  int*    cursors = (int*)(w + 352583744);             // 32 B

  (void)in_sizes; (void)n_in; (void)out_size; (void)ws_size;

  transpose_cvt<<<dim3(H_ / 64, D_ / 64, E_), 256, 0, stream>>>(W1, w1t, D_, H_);
  transpose_cvt<<<dim3(O_ / 64, H_ / 64, E_), 256, 0, stream>>>(W2, w2t, H_, O_);

  gating_k<<<B_ / 4, 256, 0, stream>>>(x, Wg, bg, out_gates, out_topi, exp_a, gate_a, x_bf);
  count_prefix_k<<<1, 256, 0, stream>>>(exp_a, counts, offs, cursors);
  scatter_k<<<64, 256, 0, stream>>>(exp_a, cursors, rows, slot_of);

  moe_gemm<1><<<dim3(H_ / 128, 20, E_), 512, 0, stream>>>(x_bf, w1t, b1, h_buf, part,
                                                          rows, counts, offs);
  moe_gemm<2><<<dim3(O_ / 128, 20, E_), 512, 0, stream>>>(h_buf, w2t, b2, h_buf, part,
                                                          rows, counts, offs);

  combine_k<<<B_ * O_ / 8 / 256, 256, 0, stream>>>(part, slot_of, gate_a, out_y);
  importance_k<<<E_, 256, 0, stream>>>(out_gates, out_load, out_imp);
}